// Round 2
// baseline (415.718 us; speedup 1.0000x reference)
//
#include <hip/hip_runtime.h>
#include <cstdint>
#include <cstddef>

#define TOK 4096
#define DM 768
#define HID 2048
#define NE 8

typedef __attribute__((ext_vector_type(8))) short bf16x8;
typedef __attribute__((ext_vector_type(4))) float f32x4;

__device__ __forceinline__ unsigned short f2bf(float f) {
  unsigned int u = __float_as_uint(f);
  u += 0x7FFF + ((u >> 16) & 1);   // RNE
  return (unsigned short)(u >> 16);
}

// ---------------- K1: gating (one wave per token) ----------------
__global__ __launch_bounds__(256)
void k_gate(const float* __restrict__ x, const float* __restrict__ wgw,
            const float* __restrict__ wgb,
            int* __restrict__ eidx, float* __restrict__ gatep,
            int* __restrict__ pos, int* __restrict__ counts,
            float* __restrict__ ce_partial)
{
  __shared__ float ce_loc[4][NE];
  const int lane = threadIdx.x & 63;
  const int w = threadIdx.x >> 6;
  const int t = blockIdx.x * 4 + w;

  float acc[NE];
#pragma unroll
  for (int e = 0; e < NE; ++e) acc[e] = 0.f;
  const float* xr = x + (size_t)t * DM;
#pragma unroll
  for (int j = 0; j < DM / 64; ++j) {
    float xv = xr[j * 64 + lane];
#pragma unroll
    for (int e = 0; e < NE; ++e) acc[e] += xv * wgw[e * DM + j * 64 + lane];
  }
#pragma unroll
  for (int e = 0; e < NE; ++e) {
    float v = acc[e];
#pragma unroll
    for (int off = 32; off >= 1; off >>= 1) v += __shfl_xor(v, off);
    acc[e] = v + wgb[e];
  }
  // first-wins argmax (numpy semantics)
  float mx = acc[0]; int ai = 0;
#pragma unroll
  for (int e = 1; e < NE; ++e) if (acc[e] > mx) { mx = acc[e]; ai = e; }
  float p[NE]; float se = 0.f;
#pragma unroll
  for (int e = 0; e < NE; ++e) { p[e] = expf(acc[e] - mx); se += p[e]; }
  float inv = 1.f / se;

  if (lane == 0) {
#pragma unroll
    for (int e = 0; e < NE; ++e) ce_loc[w][e] = p[e] * inv;
    eidx[t] = ai;
    gatep[t] = p[ai] * inv;
    pos[t] = atomicAdd(&counts[ai], 1);
  }
  __syncthreads();
  if (threadIdx.x < NE) {
    float s = ce_loc[0][threadIdx.x] + ce_loc[1][threadIdx.x]
            + ce_loc[2][threadIdx.x] + ce_loc[3][threadIdx.x];
    ce_partial[blockIdx.x * NE + threadIdx.x] = s;
  }
}

// ---------------- K2: ce reduce + offsets + aux ----------------
__global__ __launch_bounds__(256)
void k_reduce(const int* __restrict__ counts, const float* __restrict__ cepart,
              int* __restrict__ offs, float* __restrict__ aux_out)
{
  __shared__ float sl[256][NE];
  const int tid = threadIdx.x;
  float s[NE];
#pragma unroll
  for (int e = 0; e < NE; ++e) s[e] = 0.f;
  for (int b = tid; b < TOK / 4; b += 256)
#pragma unroll
    for (int e = 0; e < NE; ++e) s[e] += cepart[b * NE + e];
#pragma unroll
  for (int e = 0; e < NE; ++e) sl[tid][e] = s[e];
  __syncthreads();
  for (int st = 128; st > 0; st >>= 1) {
    if (tid < st)
#pragma unroll
      for (int e = 0; e < NE; ++e) sl[tid][e] += sl[tid + st][e];
    __syncthreads();
  }
  if (tid == 0) {
    int o = 0;
    for (int e = 0; e < NE; ++e) { offs[e] = o; o += counts[e]; }
    offs[NE] = o;
    float aux = 0.f;
    for (int e = 0; e < NE; ++e)
      aux += ((float)counts[e] / 4096.f) * (sl[0][e] / 4096.f);
    aux_out[0] = 0.05f * 8.f * aux;
  }
}

// ---------------- K3: gather x rows to bucket order, fp32->bf16 ----------------
__global__ __launch_bounds__(256)
void k_scatter(const float* __restrict__ x, const int* __restrict__ eidx,
               const float* __restrict__ gatep, const int* __restrict__ pos,
               const int* __restrict__ offs, int* __restrict__ tlist,
               float* __restrict__ gate_b, unsigned short* __restrict__ xb)
{
  const int lane = threadIdx.x & 63;
  const int w = threadIdx.x >> 6;
  const int t = blockIdx.x * 4 + w;
  const int e = eidx[t];
  const int row = offs[e] + pos[t];
  if (lane == 0) { tlist[row] = t; gate_b[row] = gatep[t]; }
  const float4* src = (const float4*)(x + (size_t)t * DM);
  uint2* dst = (uint2*)(xb + (size_t)row * DM);
#pragma unroll
  for (int c = 0; c < 3; ++c) {
    float4 v = src[lane + c * 64];
    uint2 d;
    d.x = (unsigned)f2bf(v.x) | ((unsigned)f2bf(v.y) << 16);
    d.y = (unsigned)f2bf(v.z) | ((unsigned)f2bf(v.w) << 16);
    dst[lane + c * 64] = d;
  }
}

// ---------------- D1: h = silu(x@Wu) * (x@Wv) * gate  (per expert) ----------------
// block tile 128(M) x 128(N), BK=32, 4 waves in 2x2, wave tile 64x64 per GEMM.
// LDS stores fragments in per-lane swizzled order: [sub16][lane][8k] so frag
// reads are contiguous ds_read_b128.
__global__ __launch_bounds__(256, 2)
void k_ffn1(const float* __restrict__ Wu, const float* __restrict__ Wv,
            const unsigned short* __restrict__ xb, const float* __restrict__ gate_b,
            const int* __restrict__ offs, unsigned short* __restrict__ h)
{
  const int e = blockIdx.z;
  const int m0 = offs[e];
  const int Me = offs[e + 1] - m0;
  const int tm = blockIdx.y;
  if (tm * 128 >= Me) return;       // uniform early-exit
  const int tn = blockIdx.x;

  __shared__ __align__(16) unsigned short As[4096];
  __shared__ __align__(16) unsigned short Bus[4096];
  __shared__ __align__(16) unsigned short Bvs[4096];

  const int tid = threadIdx.x;
  const int lane = tid & 63;
  const int wm = (tid >> 6) >> 1;
  const int wn = (tid >> 6) & 1;

  f32x4 accU[4][4], accV[4][4];
#pragma unroll
  for (int i = 0; i < 4; ++i)
#pragma unroll
    for (int j = 0; j < 4; ++j)
#pragma unroll
      for (int k = 0; k < 4; ++k) { accU[i][j][k] = 0.f; accV[i][j][k] = 0.f; }

  const unsigned short* xrow0 = xb + (size_t)(m0 + tm * 128) * DM;
  const float* wu0 = Wu + (size_t)e * DM * HID + tn * 128;
  const float* wv0 = Wv + (size_t)e * DM * HID + tn * 128;

  const int am0 = tid >> 2, ako = tid & 3;      // A units: (am0, ako), (am0+64, ako)
  const int bn = tid & 127, bko0 = tid >> 7;    // B units: (bn, bko0), (bn, bko0+2)

  for (int kt = 0; kt < DM / 32; ++kt) {
    // stage A (already bf16, contiguous 16B per unit)
#pragma unroll
    for (int s = 0; s < 2; ++s) {
      int m = am0 + s * 64;
      uint4 av = *(const uint4*)(xrow0 + (size_t)m * DM + kt * 32 + ako * 8);
      *(uint4*)&As[(m >> 4) * 512 + ((m & 15) + ako * 16) * 8] = av;
    }
    // stage Bu/Bv: read fp32 columns (coalesced in n), cvt, write swizzled
#pragma unroll
    for (int s = 0; s < 2; ++s) {
      int ko = bko0 + s * 2;
      int krow = kt * 32 + ko * 8;
      const float* pu = wu0 + (size_t)krow * HID + bn;
      const float* pv = wv0 + (size_t)krow * HID + bn;
      unsigned int du[4], dv[4];
#pragma unroll
      for (int jj = 0; jj < 4; ++jj) {
        du[jj] = (unsigned)f2bf(pu[(size_t)(2 * jj) * HID]) |
                 ((unsigned)f2bf(pu[(size_t)(2 * jj + 1) * HID]) << 16);
        dv[jj] = (unsigned)f2bf(pv[(size_t)(2 * jj) * HID]) |
                 ((unsigned)f2bf(pv[(size_t)(2 * jj + 1) * HID]) << 16);
      }
      int base = (bn >> 4) * 512 + ((bn & 15) + ko * 16) * 8;
      uint4 uu; uu.x = du[0]; uu.y = du[1]; uu.z = du[2]; uu.w = du[3];
      uint4 vv; vv.x = dv[0]; vv.y = dv[1]; vv.z = dv[2]; vv.w = dv[3];
      *(uint4*)&Bus[base] = uu;
      *(uint4*)&Bvs[base] = vv;
    }
    __syncthreads();
    bf16x8 a[4], bu[4], bv[4];
#pragma unroll
    for (int i = 0; i < 4; ++i) a[i] = *(const bf16x8*)&As[(wm * 4 + i) * 512 + lane * 8];
#pragma unroll
    for (int j = 0; j < 4; ++j) {
      bu[j] = *(const bf16x8*)&Bus[(wn * 4 + j) * 512 + lane * 8];
      bv[j] = *(const bf16x8*)&Bvs[(wn * 4 + j) * 512 + lane * 8];
    }
#pragma unroll
    for (int i = 0; i < 4; ++i)
#pragma unroll
      for (int j = 0; j < 4; ++j) {
        accU[i][j] = __builtin_amdgcn_mfma_f32_16x16x32_bf16(a[i], bu[j], accU[i][j], 0, 0, 0);
        accV[i][j] = __builtin_amdgcn_mfma_f32_16x16x32_bf16(a[i], bv[j], accV[i][j], 0, 0, 0);
      }
    __syncthreads();
  }
  // epilogue: h = silu(u)*v*gate, bf16; C/D layout col=lane&15, row=quad*4+reg
  const int colbase = tn * 128 + wn * 64;
  const int rlane = (lane >> 4) * 4;
  const int clane = lane & 15;
#pragma unroll
  for (int i = 0; i < 4; ++i) {
#pragma unroll
    for (int r = 0; r < 4; ++r) {
      int rowIn = wm * 64 + i * 16 + rlane + r;
      if (tm * 128 + rowIn < Me) {
        int grow = m0 + tm * 128 + rowIn;
        float g = gate_b[grow];
        unsigned short* hp = h + (size_t)grow * HID + colbase + clane;
#pragma unroll
        for (int j = 0; j < 4; ++j) {
          float u_ = accU[i][j][r];
          float v_ = accV[i][j][r];
          float sv = u_ / (1.f + expf(-u_));
          hp[j * 16] = f2bf(sv * v_ * g);
        }
      }
    }
  }
}

// ---------------- D2: y = h @ Wd, scatter to token order ----------------
// block tile 64(M) x 128(N), BK=32, 4 waves 2x2, wave tile 32x64.
// gridDim.x padded to 8 so same-(e,tn) blocks land on the same XCD (stride%8==0).
__global__ __launch_bounds__(256, 2)
void k_ffn2(const float* __restrict__ Wd, const unsigned short* __restrict__ h,
            const int* __restrict__ offs, const int* __restrict__ tlist,
            float* __restrict__ y)
{
  const int tn = blockIdx.x;
  if (tn >= 6) return;
  const int e = blockIdx.z;
  const int m0 = offs[e];
  const int Me = offs[e + 1] - m0;
  const int tm = blockIdx.y;
  if (tm * 64 >= Me) return;

  __shared__ __align__(16) unsigned short As[2048];
  __shared__ __align__(16) unsigned short Bs[4096];

  const int tid = threadIdx.x;
  const int lane = tid & 63;
  const int wm = (tid >> 6) >> 1;
  const int wn = (tid >> 6) & 1;

  f32x4 acc[2][4];
#pragma unroll
  for (int i = 0; i < 2; ++i)
#pragma unroll
    for (int j = 0; j < 4; ++j)
#pragma unroll
      for (int k = 0; k < 4; ++k) acc[i][j][k] = 0.f;

  const unsigned short* hrow0 = h + (size_t)(m0 + tm * 64) * HID;
  const float* wd0 = Wd + (size_t)e * HID * DM + tn * 128;

  const int am = tid >> 2, ako = tid & 3;
  const int bn = tid & 127, bko0 = tid >> 7;

  for (int kt = 0; kt < HID / 32; ++kt) {
    uint4 av = *(const uint4*)(hrow0 + (size_t)am * HID + kt * 32 + ako * 8);
    *(uint4*)&As[(am >> 4) * 512 + ((am & 15) + ako * 16) * 8] = av;
#pragma unroll
    for (int s = 0; s < 2; ++s) {
      int ko = bko0 + s * 2;
      int krow = kt * 32 + ko * 8;
      const float* pb = wd0 + (size_t)krow * DM + bn;
      unsigned int d[4];
#pragma unroll
      for (int jj = 0; jj < 4; ++jj)
        d[jj] = (unsigned)f2bf(pb[(size_t)(2 * jj) * DM]) |
                ((unsigned)f2bf(pb[(size_t)(2 * jj + 1) * DM]) << 16);
      uint4 bb; bb.x = d[0]; bb.y = d[1]; bb.z = d[2]; bb.w = d[3];
      *(uint4*)&Bs[(bn >> 4) * 512 + ((bn & 15) + ko * 16) * 8] = bb;
    }
    __syncthreads();
    bf16x8 a[2], b[4];
#pragma unroll
    for (int i = 0; i < 2; ++i) a[i] = *(const bf16x8*)&As[(wm * 2 + i) * 512 + lane * 8];
#pragma unroll
    for (int j = 0; j < 4; ++j) b[j] = *(const bf16x8*)&Bs[(wn * 4 + j) * 512 + lane * 8];
#pragma unroll
    for (int i = 0; i < 2; ++i)
#pragma unroll
      for (int j = 0; j < 4; ++j)
        acc[i][j] = __builtin_amdgcn_mfma_f32_16x16x32_bf16(a[i], b[j], acc[i][j], 0, 0, 0);
    __syncthreads();
  }
  const int colbase = tn * 128 + wn * 64;
  const int rlane = (lane >> 4) * 4;
  const int clane = lane & 15;
#pragma unroll
  for (int i = 0; i < 2; ++i) {
#pragma unroll
    for (int r = 0; r < 4; ++r) {
      int rowIn = wm * 32 + i * 16 + rlane + r;
      if (tm * 64 + rowIn < Me) {
        int tok = tlist[m0 + tm * 64 + rowIn];
        float* yp = y + (size_t)tok * DM + colbase + clane;
#pragma unroll
        for (int j = 0; j < 4; ++j) yp[j * 16] = acc[i][j][r];
      }
    }
  }
}

extern "C" void kernel_launch(void* const* d_in, const int* in_sizes, int n_in,
                              void* d_out, int out_size, void* d_ws, size_t ws_size,
                              hipStream_t stream)
{
  const float* x   = (const float*)d_in[0];
  const float* wgw = (const float*)d_in[1];
  const float* wgb = (const float*)d_in[2];
  const float* Wu  = (const float*)d_in[3];
  const float* Wv  = (const float*)d_in[4];
  const float* Wd  = (const float*)d_in[5];
  float* out = (float*)d_out;

  // workspace layout (needs ~23.9 MB)
  char* ws = (char*)d_ws;
  int*   eidx   = (int*)(ws + 0);            // 4096 ints
  float* gatep  = (float*)(ws + 16384);      // 4096 f
  int*   pos    = (int*)(ws + 32768);        // 4096 ints
  int*   counts = (int*)(ws + 49152);        // 8 ints
  int*   offs   = (int*)(ws + 49216);        // 9 ints
  float* cepart = (float*)(ws + 49664);      // 1024*8 f
  int*   tlist  = (int*)(ws + 82432);        // 4096 ints
  float* gate_b = (float*)(ws + 98816);      // 4224 f
  unsigned short* xb = (unsigned short*)(ws + 115712);   // 4224*768 bf16
  unsigned short* h  = (unsigned short*)(ws + 6603776);  // 4224*2048 bf16

  hipMemsetAsync(counts, 0, 64, stream);
  k_gate<<<TOK / 4, 256, 0, stream>>>(x, wgw, wgb, eidx, gatep, pos, counts, cepart);
  // y is (2,2048,768) = 3,145,728 floats; aux scalar follows immediately.
  k_reduce<<<1, 256, 0, stream>>>(counts, cepart, offs, out + (size_t)TOK * DM);
  k_scatter<<<TOK / 4, 256, 0, stream>>>(x, eidx, gatep, pos, offs, tlist, gate_b, xb);
  k_ffn1<<<dim3(16, 32, 8), 256, 0, stream>>>(Wu, Wv, xb, gate_b, offs, h);
  k_ffn2<<<dim3(8, 64, 8), 256, 0, stream>>>(Wd, h, offs, tlist, out);
}

// Round 5
// 378.911 us; speedup vs baseline: 1.0971x; 1.0971x over previous
//
#include <hip/hip_runtime.h>
#include <cstdint>
#include <cstddef>

#define TOK 4096
#define DM 768
#define HID 2048
#define NE 8

typedef __attribute__((ext_vector_type(8))) short bf16x8;
typedef __attribute__((ext_vector_type(4))) float f32x4;

// async global->LDS, 16B per lane; LDS dest must be wave-uniform base.
#define ASYNC16(GP, LP) \
  __builtin_amdgcn_global_load_lds((__attribute__((address_space(1))) void*)(GP), \
                                   (__attribute__((address_space(3))) void*)(LP), 16, 0, 0)

__device__ __forceinline__ unsigned short f2bf(float f) {
  unsigned int u = __float_as_uint(f);
  u += 0x7FFF + ((u >> 16) & 1);   // RNE
  return (unsigned short)(u >> 16);
}
__device__ __forceinline__ unsigned int pack2(float a, float b) {
  return (unsigned)f2bf(a) | ((unsigned)f2bf(b) << 16);
}
__device__ __forceinline__ int padded_off(const int* counts, int e) {
  int o = 0;
  for (int i = 0; i < e; ++i) o += (counts[i] + 127) & ~127;
  return o;
}

// Blob layout (per 128n x 32k tile, 8192 B = 512 16B-units): unit holds 8
// k-consecutive bf16 for one n; slot(n,ko) = n*4 + (ko ^ (n&3)) — xor swizzle
// keeps frag ds_read_b128 at <=2-way bank conflict (free, m136) while staging
// stays linear for ASYNC16.

// ---------------- K1: gating + weight convert ----------------
__global__ __launch_bounds__(256)
void k1_gate_convert(const float* __restrict__ x, const float* __restrict__ wgw,
                     const float* __restrict__ wgb,
                     const float* __restrict__ Wu, const float* __restrict__ Wv,
                     const float* __restrict__ Wd,
                     int* __restrict__ eidx, float* __restrict__ gatep,
                     int* __restrict__ pos, int* __restrict__ counts,
                     float* __restrict__ cepart,
                     unsigned short* __restrict__ wub, unsigned short* __restrict__ wvb,
                     unsigned short* __restrict__ wdb)
{
  __shared__ float ce_loc[4][NE];
  const int b = blockIdx.x;
  if (b < 1024) {
    // ---- gating: one wave per token ----
    const int lane = threadIdx.x & 63;
    const int w = threadIdx.x >> 6;
    const int t = b * 4 + w;
    float acc[NE];
#pragma unroll
    for (int e = 0; e < NE; ++e) acc[e] = 0.f;
    const float* xr = x + (size_t)t * DM;
#pragma unroll
    for (int j = 0; j < DM / 64; ++j) {
      float xv = xr[j * 64 + lane];
#pragma unroll
      for (int e = 0; e < NE; ++e) acc[e] += xv * wgw[e * DM + j * 64 + lane];
    }
#pragma unroll
    for (int e = 0; e < NE; ++e) {
      float v = acc[e];
#pragma unroll
      for (int off = 32; off >= 1; off >>= 1) v += __shfl_xor(v, off);
      acc[e] = v + wgb[e];
    }
    float mx = acc[0]; int ai = 0;
#pragma unroll
    for (int e = 1; e < NE; ++e) if (acc[e] > mx) { mx = acc[e]; ai = e; }
    float p[NE]; float se = 0.f;
#pragma unroll
    for (int e = 0; e < NE; ++e) { p[e] = expf(acc[e] - mx); se += p[e]; }
    float inv = 1.f / se;
    if (lane == 0) {
#pragma unroll
      for (int e = 0; e < NE; ++e) ce_loc[w][e] = p[e] * inv;
      eidx[t] = ai;
      gatep[t] = p[ai] * inv;
      pos[t] = atomicAdd(&counts[ai], 1);
    }
    __syncthreads();
    if (threadIdx.x < NE) {
      float s = ce_loc[0][threadIdx.x] + ce_loc[1][threadIdx.x]
              + ce_loc[2][threadIdx.x] + ce_loc[3][threadIdx.x];
      cepart[b * NE + threadIdx.x] = s;
    }
    return;
  }
  // ---- weight convert: one 128n x 32k blob (8 KB, 512 16B-units) per block ----
  const int cb = b - 1024;
  const int seg = cb / 3072;         // 0=Wu 1=Wv 2=Wd
  const int r = cb % 3072;
  const int e = r / 384;
  const int rem = r % 384;
  const float* W;
  unsigned short* blob;
  int N, nt, kt;
  if (seg < 2) {
    N = HID; nt = rem / 24; kt = rem % 24;
    W = (seg == 0) ? Wu : Wv;
    blob = ((seg == 0) ? wub : wvb) + (size_t)((e * 16 + nt) * 24 + kt) * 4096;
    W += (size_t)e * DM * HID;
  } else {
    N = DM; nt = rem / 64; kt = rem % 64;
    W = Wd + (size_t)e * HID * DM;
    blob = wdb + (size_t)((e * 6 + nt) * 64 + kt) * 4096;
  }
  const int t = threadIdx.x;
#pragma unroll
  for (int c = 0; c < 2; ++c) {
    const int unit = c * 256 + t;             // 512 units cover full 128n x 4ko
    const int nl = unit >> 2, s = unit & 3, ko = s ^ (nl & 3);
    const float* src = W + (size_t)(kt * 32 + ko * 8) * N + nt * 128 + nl;
    uint4 u;
    u.x = pack2(src[0], src[(size_t)N]);
    u.y = pack2(src[(size_t)2 * N], src[(size_t)3 * N]);
    u.z = pack2(src[(size_t)4 * N], src[(size_t)5 * N]);
    u.w = pack2(src[(size_t)6 * N], src[(size_t)7 * N]);
    *(uint4*)(blob + (size_t)unit * 8) = u;
  }
}

// ---------------- K2: scatter x to A-blobs + zero y + aux ----------------
__global__ __launch_bounds__(256)
void k2_scatter_zero_aux(const float* __restrict__ x, const int* __restrict__ eidx,
                         const float* __restrict__ gatep, const int* __restrict__ pos,
                         const int* __restrict__ counts, const float* __restrict__ cepart,
                         int* __restrict__ tlist, float* __restrict__ gate_b,
                         unsigned short* __restrict__ xb,
                         float* __restrict__ y, float* __restrict__ aux_out)
{
  __shared__ float sl[256][NE];
  const int b = blockIdx.x;
  if (b < 1024) {
    const int lane = threadIdx.x & 63;
    const int w = threadIdx.x >> 6;
    const int t = b * 4 + w;
    const int e = eidx[t];
    const int prow = padded_off(counts, e) + pos[t];
    if (lane == 0) { tlist[prow] = t; gate_b[prow] = gatep[t]; }
    const int tile = prow >> 7, m = prow & 127;
    const float* xr = x + (size_t)t * DM;
#pragma unroll
    for (int c = 0; c < 2; ++c) {
      int u = c * 64 + lane;
      if (u < 96) {
        int kt = u >> 2, ko = u & 3;
        const float4* s4 = (const float4*)(xr + kt * 32 + ko * 8);
        float4 v0 = s4[0], v1 = s4[1];
        uint4 d;
        d.x = pack2(v0.x, v0.y); d.y = pack2(v0.z, v0.w);
        d.z = pack2(v1.x, v1.y); d.w = pack2(v1.z, v1.w);
        int slot = m * 4 + (ko ^ (m & 3));
        // slab stride = 512 units (8 KB) — matches reader's kt<<13
        *(uint4*)(xb + ((size_t)(tile * 24 + kt) * 512 + slot) * 8) = d;
      }
    }
  } else if (b < 1536) {
    // zero y: 512 blocks * 256 thr * 6 float4 = 3,145,728 floats
    float4* y4 = (float4*)y;
    const int base = (b - 1024) * 1536 + threadIdx.x;
#pragma unroll
    for (int c = 0; c < 6; ++c) {
      float4 z; z.x = 0.f; z.y = 0.f; z.z = 0.f; z.w = 0.f;
      y4[base + c * 256] = z;
    }
  } else {
    // aux reduce
    const int tid = threadIdx.x;
    float s[NE];
#pragma unroll
    for (int e = 0; e < NE; ++e) s[e] = 0.f;
    for (int bb = tid; bb < 1024; bb += 256)
#pragma unroll
      for (int e = 0; e < NE; ++e) s[e] += cepart[bb * NE + e];
#pragma unroll
    for (int e = 0; e < NE; ++e) sl[tid][e] = s[e];
    __syncthreads();
    for (int st = 128; st > 0; st >>= 1) {
      if (tid < st)
#pragma unroll
        for (int e = 0; e < NE; ++e) sl[tid][e] += sl[tid + st][e];
      __syncthreads();
    }
    if (tid == 0) {
      float aux = 0.f;
      for (int e = 0; e < NE; ++e)
        aux += ((float)counts[e] / 4096.f) * (sl[0][e] / 4096.f);
      aux_out[0] = 0.05f * 8.f * aux;
    }
  }
}

// ---------------- FFN1: h = silu(x@Wu)*(x@Wv)*gate ----------------
// 128M x 128N, BK=32, waves 2x2 (64x64/wave/GEMM). All staging = ASYNC16.
__global__ __launch_bounds__(256, 2)
void k_ffn1(const unsigned short* __restrict__ wub, const unsigned short* __restrict__ wvb,
            const unsigned short* __restrict__ xb, const float* __restrict__ gate_b,
            const int* __restrict__ counts, unsigned short* __restrict__ h)
{
  const int e = blockIdx.z;
  const int Me = counts[e];
  const int tm = blockIdx.y;
  if (tm * 128 >= Me) return;
  const int tn = blockIdx.x;
  const int prowbase = padded_off(counts, e) + tm * 128;
  const int atile = prowbase >> 7;

  __shared__ __align__(16) unsigned short Sh[12288];  // [A 8KB][Bu 8KB][Bv 8KB]

  const int tid = threadIdx.x;
  const int lane = tid & 63;
  const int wv_ = tid >> 6;
  const int wm = wv_ >> 1, wn = wv_ & 1;
  const int wu_id = __builtin_amdgcn_readfirstlane(wv_);

  f32x4 accU[4][4], accV[4][4];
#pragma unroll
  for (int i = 0; i < 4; ++i)
#pragma unroll
    for (int j = 0; j < 4; ++j)
#pragma unroll
      for (int k = 0; k < 4; ++k) { accU[i][j][k] = 0.f; accV[i][j][k] = 0.f; }

  const char* AbBase = (const char*)xb + ((size_t)(atile * 24) << 13);
  const char* BuBase = (const char*)wub + ((size_t)((e * 16 + tn) * 24) << 13);
  const char* BvBase = (const char*)wvb + ((size_t)((e * 16 + tn) * 24) << 13);
  const int lc = lane & 15, q = lane >> 4;

  for (int kt = 0; kt < 24; ++kt) {
    const char* Ab = AbBase + ((size_t)kt << 13);
    const char* Bub = BuBase + ((size_t)kt << 13);
    const char* Bvb = BvBase + ((size_t)kt << 13);
#pragma unroll
    for (int c2 = 0; c2 < 6; ++c2) {
      const int c = wu_id * 6 + c2;            // scalar: uniform branch
      const char* g;
      if (c < 8)       g = Ab + c * 1024 + lane * 16;
      else if (c < 16) g = Bub + (c - 8) * 1024 + lane * 16;
      else             g = Bvb + (c - 16) * 1024 + lane * 16;
      ASYNC16(g, (char*)Sh + (unsigned)(c * 1024));
    }
    __syncthreads();
    bf16x8 a[4], bu[4], bv[4];
#pragma unroll
    for (int i = 0; i < 4; ++i) {
      int m = wm * 64 + i * 16 + lc;
      a[i] = *(const bf16x8*)&Sh[(m * 4 + (q ^ (m & 3))) * 8];
    }
#pragma unroll
    for (int j = 0; j < 4; ++j) {
      int n = wn * 64 + j * 16 + lc;
      int slb = (n * 4 + (q ^ (n & 3))) * 8;
      bu[j] = *(const bf16x8*)&Sh[4096 + slb];
      bv[j] = *(const bf16x8*)&Sh[8192 + slb];
    }
#pragma unroll
    for (int i = 0; i < 4; ++i)
#pragma unroll
      for (int j = 0; j < 4; ++j) {
        accU[i][j] = __builtin_amdgcn_mfma_f32_16x16x32_bf16(a[i], bu[j], accU[i][j], 0, 0, 0);
        accV[i][j] = __builtin_amdgcn_mfma_f32_16x16x32_bf16(a[i], bv[j], accV[i][j], 0, 0, 0);
      }
    __syncthreads();
  }
  const int colbase = tn * 128 + wn * 64;
  const int rlane = (lane >> 4) * 4;
  const int clane = lane & 15;
#pragma unroll
  for (int i = 0; i < 4; ++i) {
#pragma unroll
    for (int r = 0; r < 4; ++r) {
      int rowIn = wm * 64 + i * 16 + rlane + r;
      if (tm * 128 + rowIn < Me) {
        int prow = prowbase + rowIn;
        float g = gate_b[prow];
        unsigned short* hp = h + (size_t)prow * HID + colbase + clane;
#pragma unroll
        for (int j = 0; j < 4; ++j) {
          float u_ = accU[i][j][r];
          float v_ = accV[i][j][r];
          float sv = u_ / (1.f + expf(-u_));
          hp[j * 16] = f2bf(sv * v_ * g);
        }
      }
    }
  }
}

// ---------------- FFN2: y += h @ Wd (split-K=4, atomic f32) ----------------
// 128M x 128N, BK=32, waves 2x2. A staged from row-major h via per-lane ASYNC16.
__global__ __launch_bounds__(256, 2)
void k_ffn2(const unsigned short* __restrict__ wdb, const unsigned short* __restrict__ h,
            const int* __restrict__ counts, const int* __restrict__ tlist,
            float* __restrict__ y)
{
  const int z = blockIdx.z;
  const int e = z >> 2, split = z & 3;
  const int Me = counts[e];
  const int tm = blockIdx.y;
  if (tm * 128 >= Me) return;
  const int tn = blockIdx.x;
  const int prowbase = padded_off(counts, e) + tm * 128;

  __shared__ __align__(16) unsigned short Sh[8192];  // [A 8KB][B 8KB]

  const int tid = threadIdx.x;
  const int lane = tid & 63;
  const int wv_ = tid >> 6;
  const int wm = wv_ >> 1, wn = wv_ & 1;
  const int wu_id = __builtin_amdgcn_readfirstlane(wv_);

  f32x4 acc[4][4];
#pragma unroll
  for (int i = 0; i < 4; ++i)
#pragma unroll
    for (int j = 0; j < 4; ++j)
#pragma unroll
      for (int k = 0; k < 4; ++k) acc[i][j][k] = 0.f;

  const char* hB = (const char*)h + (size_t)prowbase * (HID * 2);
  const char* BdBase = (const char*)wdb + ((size_t)((e * 6 + tn) * 64) << 13);
  const int lc = lane & 15, q = lane >> 4;

  for (int kti = 0; kti < 16; ++kti) {
    const int ktg = split * 16 + kti;
    const char* Bb = BdBase + ((size_t)ktg << 13);
#pragma unroll
    for (int c2 = 0; c2 < 4; ++c2) {
      const int c = wu_id * 4 + c2;
      const char* g;
      if (c < 8) {
        int mrow = c * 16 + (lane >> 2);
        int ko = (lane & 3) ^ (mrow & 3);
        g = hB + (size_t)mrow * (HID * 2) + ktg * 64 + ko * 16;
      } else {
        g = Bb + (c - 8) * 1024 + lane * 16;
      }
      ASYNC16(g, (char*)Sh + (unsigned)(c * 1024));
    }
    __syncthreads();
    bf16x8 a[4], bfr[4];
#pragma unroll
    for (int i = 0; i < 4; ++i) {
      int m = wm * 64 + i * 16 + lc;
      a[i] = *(const bf16x8*)&Sh[(m * 4 + (q ^ (m & 3))) * 8];
    }
#pragma unroll
    for (int j = 0; j < 4; ++j) {
      int n = wn * 64 + j * 16 + lc;
      bfr[j] = *(const bf16x8*)&Sh[4096 + (n * 4 + (q ^ (n & 3))) * 8];
    }
#pragma unroll
    for (int i = 0; i < 4; ++i)
#pragma unroll
      for (int j = 0; j < 4; ++j)
        acc[i][j] = __builtin_amdgcn_mfma_f32_16x16x32_bf16(a[i], bfr[j], acc[i][j], 0, 0, 0);
    __syncthreads();
  }
  const int colbase = tn * 128 + wn * 64;
  const int rlane = (lane >> 4) * 4;
  const int clane = lane & 15;
#pragma unroll
  for (int i = 0; i < 4; ++i) {
#pragma unroll
    for (int r = 0; r < 4; ++r) {
      int rowIn = wm * 64 + i * 16 + rlane + r;
      if (tm * 128 + rowIn < Me) {
        int tok = tlist[prowbase + rowIn];
        float* yp = y + (size_t)tok * DM + colbase + clane;
#pragma unroll
        for (int j = 0; j < 4; ++j) atomicAdd(&yp[j * 16], acc[i][j][r]);
      }
    }
  }
}

extern "C" void kernel_launch(void* const* d_in, const int* in_sizes, int n_in,
                              void* d_out, int out_size, void* d_ws, size_t ws_size,
                              hipStream_t stream)
{
  const float* x   = (const float*)d_in[0];
  const float* wgw = (const float*)d_in[1];
  const float* wgb = (const float*)d_in[2];
  const float* Wu  = (const float*)d_in[3];
  const float* Wv  = (const float*)d_in[4];
  const float* Wd  = (const float*)d_in[5];
  float* out = (float*)d_out;

  // ws layout (~104.5 MB total)
  char* ws = (char*)d_ws;
  int*   counts = (int*)(ws + 0);                         // 8 ints
  int*   eidx   = (int*)(ws + 256);                       // 4096
  float* gatep  = (float*)(ws + 16640);                   // 4096
  int*   pos    = (int*)(ws + 33024);                     // 4096
  float* cepart = (float*)(ws + 49408);                   // 1024*8
  int*   tlist  = (int*)(ws + 82176);                     // 5120 (padded rows)
  float* gate_b = (float*)(ws + 102656);                  // 5120
  unsigned short* xb  = (unsigned short*)(ws + 123136);   // 40*24*8192 B = 7.86 MB
  unsigned short* h   = (unsigned short*)(ws + 7987456);  // 5120*2048 bf16 = 21 MB
  unsigned short* wub = (unsigned short*)(ws + 28958976); // 25.2 MB
  unsigned short* wvb = (unsigned short*)(ws + 54124800); // 25.2 MB
  unsigned short* wdb = (unsigned short*)(ws + 79290624); // 25.2 MB

  hipMemsetAsync(counts, 0, 32, stream);
  k1_gate_convert<<<10240, 256, 0, stream>>>(x, wgw, wgb, Wu, Wv, Wd,
                                             eidx, gatep, pos, counts, cepart,
                                             wub, wvb, wdb);
  k2_scatter_zero_aux<<<1537, 256, 0, stream>>>(x, eidx, gatep, pos, counts, cepart,
                                                tlist, gate_b, xb,
                                                out, out + (size_t)TOK * DM);
  k_ffn1<<<dim3(16, 32, 8), 256, 0, stream>>>(wub, wvb, xb, gate_b, counts, h);
  k_ffn2<<<dim3(6, 32, 32), 256, 0, stream>>>(wdb, h, counts, tlist, out);
}

// Round 6
// 375.933 us; speedup vs baseline: 1.1058x; 1.0079x over previous
//
#include <hip/hip_runtime.h>
#include <cstdint>
#include <cstddef>

#define TOK 4096
#define DM 768
#define HID 2048
#define NE 8

typedef __attribute__((ext_vector_type(8))) short bf16x8;
typedef __attribute__((ext_vector_type(4))) float f32x4;

// async global->LDS: dest = wave-uniform base + lane*16; SOURCE is per-lane.
#define ASYNC16(GP, LP) \
  __builtin_amdgcn_global_load_lds((__attribute__((address_space(1))) void*)(GP), \
                                   (__attribute__((address_space(3))) void*)(LP), 16, 0, 0)

__device__ __forceinline__ unsigned short f2bf(float f) {
  unsigned int u = __float_as_uint(f);
  u += 0x7FFF + ((u >> 16) & 1);   // RNE
  return (unsigned short)(u >> 16);
}
__device__ __forceinline__ unsigned int pack2(float a, float b) {
  return (unsigned)f2bf(a) | ((unsigned)f2bf(b) << 16);
}
__device__ __forceinline__ int padded_off(const int* counts, int e) {
  int o = 0;
  for (int i = 0; i < e; ++i) o += (counts[i] + 127) & ~127;
  return o;
}

// Weight blob layout: per (expert, 128-col tile): K/32 slabs of 8192 B.
// Slab unit u = ko*128 + n (16 B = 8 k-consecutive bf16 for one n).
// GEMM staging gathers unit (n = s>>2, ko = (s&3)^(n&3)) into LDS slot s, so
// the LDS image is the same swizzled layout the frag readers already use.

// ---------------- K1: gating + weight convert ----------------
__global__ __launch_bounds__(256)
void k1_gate_convert(const float* __restrict__ x, const float* __restrict__ wgw,
                     const float* __restrict__ wgb,
                     const float* __restrict__ Wu, const float* __restrict__ Wv,
                     const float* __restrict__ Wd,
                     int* __restrict__ eidx, float* __restrict__ gatep,
                     int* __restrict__ pos, int* __restrict__ counts,
                     float* __restrict__ cepart,
                     unsigned short* __restrict__ wub, unsigned short* __restrict__ wvb,
                     unsigned short* __restrict__ wdb)
{
  __shared__ float ce_loc[4][NE];
  const int b = blockIdx.x;
  if (b < 1024) {
    // ---- gating: one wave per token ----
    const int lane = threadIdx.x & 63;
    const int w = threadIdx.x >> 6;
    const int t = b * 4 + w;
    float acc[NE];
#pragma unroll
    for (int e = 0; e < NE; ++e) acc[e] = 0.f;
    const float* xr = x + (size_t)t * DM;
#pragma unroll
    for (int j = 0; j < DM / 64; ++j) {
      float xv = xr[j * 64 + lane];
#pragma unroll
      for (int e = 0; e < NE; ++e) acc[e] += xv * wgw[e * DM + j * 64 + lane];
    }
#pragma unroll
    for (int e = 0; e < NE; ++e) {
      float v = acc[e];
#pragma unroll
      for (int off = 32; off >= 1; off >>= 1) v += __shfl_xor(v, off);
      acc[e] = v + wgb[e];
    }
    float mx = acc[0]; int ai = 0;
#pragma unroll
    for (int e = 1; e < NE; ++e) if (acc[e] > mx) { mx = acc[e]; ai = e; }
    float p[NE]; float se = 0.f;
#pragma unroll
    for (int e = 0; e < NE; ++e) { p[e] = expf(acc[e] - mx); se += p[e]; }
    float inv = 1.f / se;
    if (lane == 0) {
#pragma unroll
      for (int e = 0; e < NE; ++e) ce_loc[w][e] = p[e] * inv;
      eidx[t] = ai;
      gatep[t] = p[ai] * inv;
      pos[t] = atomicAdd(&counts[ai], 1);
    }
    __syncthreads();
    if (threadIdx.x < NE) {
      float s = ce_loc[0][threadIdx.x] + ce_loc[1][threadIdx.x]
              + ce_loc[2][threadIdx.x] + ce_loc[3][threadIdx.x];
      cepart[b * NE + threadIdx.x] = s;
    }
    return;
  }
  // ---- weight convert: one 128n x 64k region (2 slabs) per block ----
  // Reads: 8x float4 per thread, fully coalesced. In-register transpose.
  // Writes: 4x uint4 per thread, consecutive units across lanes.
  const int cb = b - 1024;                 // 0..4607
  const int seg = cb / 1536;               // 0=Wu 1=Wv 2=Wd
  const int r = cb % 1536;
  const int e = r / 192;
  const int rem = r % 192;
  const float* W;
  unsigned short* blobbase;
  int N, nt, kt2;
  if (seg < 2) {
    N = HID; nt = rem / 12; kt2 = rem % 12;            // K=768: 12 x 64k
    W = ((seg == 0) ? Wu : Wv) + (size_t)e * DM * HID;
    blobbase = ((seg == 0) ? wub : wvb) + ((size_t)((e * 16 + nt) * 24) << 12);
  } else {
    N = DM; nt = rem / 32; kt2 = rem % 32;             // K=2048: 32 x 64k
    W = Wd + (size_t)e * HID * DM;
    blobbase = wdb + ((size_t)((e * 6 + nt) * 64) << 12);
  }
  const int t = threadIdx.x;
  const int n4 = t & 31, ko8 = t >> 5;                 // 32 n-quads x 8 k-octets
  const float* src = W + (size_t)(kt2 * 64 + ko8 * 8) * N + nt * 128 + n4 * 4;
  float4 f[8];
#pragma unroll
  for (int j = 0; j < 8; ++j) f[j] = *(const float4*)(src + (size_t)j * N);
  const int kt = kt2 * 2 + (ko8 >> 2), ko = ko8 & 3;
  unsigned short* dst = blobbase + ((size_t)kt << 12) + (size_t)(ko * 128 + n4 * 4) * 8;
#pragma unroll
  for (int i = 0; i < 4; ++i) {
    uint4 u;
    u.x = pack2(((const float*)&f[0])[i], ((const float*)&f[1])[i]);
    u.y = pack2(((const float*)&f[2])[i], ((const float*)&f[3])[i]);
    u.z = pack2(((const float*)&f[4])[i], ((const float*)&f[5])[i]);
    u.w = pack2(((const float*)&f[6])[i], ((const float*)&f[7])[i]);
    *(uint4*)(dst + i * 8) = u;
  }
}

// ---------------- K2: scatter x rows (row-major bf16) + zero y + aux ----------------
__global__ __launch_bounds__(256)
void k2_scatter_zero_aux(const float* __restrict__ x, const int* __restrict__ eidx,
                         const float* __restrict__ gatep, const int* __restrict__ pos,
                         const int* __restrict__ counts, const float* __restrict__ cepart,
                         int* __restrict__ tlist, float* __restrict__ gate_b,
                         unsigned short* __restrict__ xb,
                         float* __restrict__ y, float* __restrict__ aux_out)
{
  __shared__ float sl[256][NE];
  const int b = blockIdx.x;
  if (b < 1024) {
    const int lane = threadIdx.x & 63;
    const int w = threadIdx.x >> 6;
    const int t = b * 4 + w;
    const int e = eidx[t];
    const int prow = padded_off(counts, e) + pos[t];
    if (lane == 0) { tlist[prow] = t; gate_b[prow] = gatep[t]; }
    const float4* src4 = (const float4*)(x + (size_t)t * DM);
    uint2* dst = (uint2*)(xb + (size_t)prow * DM);
#pragma unroll
    for (int c = 0; c < 3; ++c) {
      float4 v = src4[lane + c * 64];
      uint2 d; d.x = pack2(v.x, v.y); d.y = pack2(v.z, v.w);
      dst[lane + c * 64] = d;
    }
  } else if (b < 1536) {
    float4* y4 = (float4*)y;
    const int base = (b - 1024) * 1536 + threadIdx.x;
#pragma unroll
    for (int c = 0; c < 6; ++c) {
      float4 z; z.x = 0.f; z.y = 0.f; z.z = 0.f; z.w = 0.f;
      y4[base + c * 256] = z;
    }
  } else {
    const int tid = threadIdx.x;
    float s[NE];
#pragma unroll
    for (int e = 0; e < NE; ++e) s[e] = 0.f;
    for (int bb = tid; bb < 1024; bb += 256)
#pragma unroll
      for (int e = 0; e < NE; ++e) s[e] += cepart[bb * NE + e];
#pragma unroll
    for (int e = 0; e < NE; ++e) sl[tid][e] = s[e];
    __syncthreads();
    for (int st = 128; st > 0; st >>= 1) {
      if (tid < st)
#pragma unroll
        for (int e = 0; e < NE; ++e) sl[tid][e] += sl[tid + st][e];
      __syncthreads();
    }
    if (tid == 0) {
      float aux = 0.f;
      for (int e = 0; e < NE; ++e)
        aux += ((float)counts[e] / 4096.f) * (sl[0][e] / 4096.f);
      aux_out[0] = 0.05f * 8.f * aux;
    }
  }
}

// ---------------- FFN1: h = silu(x@Wu)*(x@Wv)*gate ----------------
// 128M x 128N, BK=32, waves 2x2 (64x64/wave/GEMM). Per-lane-gather ASYNC16.
__global__ __launch_bounds__(256, 2)
void k_ffn1(const unsigned short* __restrict__ wub, const unsigned short* __restrict__ wvb,
            const unsigned short* __restrict__ xb, const float* __restrict__ gate_b,
            const int* __restrict__ counts, unsigned short* __restrict__ h)
{
  const int e = blockIdx.z;
  const int Me = counts[e];
  const int tm = blockIdx.y;
  if (tm * 128 >= Me) return;
  const int tn = blockIdx.x;
  const int prowbase = padded_off(counts, e) + tm * 128;

  __shared__ __align__(16) unsigned short Sh[12288];  // [A 8KB][Bu 8KB][Bv 8KB]

  const int tid = threadIdx.x;
  const int lane = tid & 63;
  const int wv_ = tid >> 6;
  const int wm = wv_ >> 1, wn = wv_ & 1;
  const int wu_id = __builtin_amdgcn_readfirstlane(wv_);

  f32x4 accU[4][4], accV[4][4];
#pragma unroll
  for (int i = 0; i < 4; ++i)
#pragma unroll
    for (int j = 0; j < 4; ++j)
#pragma unroll
      for (int k = 0; k < 4; ++k) { accU[i][j][k] = 0.f; accV[i][j][k] = 0.f; }

  const char* BuBase = (const char*)wub + ((size_t)((e * 16 + tn) * 24) << 13);
  const char* BvBase = (const char*)wvb + ((size_t)((e * 16 + tn) * 24) << 13);

  // per-lane gather sources: LDS slot s holds unit (n=s>>2, ko=(s&3)^(n&3))
  const char* sp[6]; size_t stp[6];
#pragma unroll
  for (int c2 = 0; c2 < 6; ++c2) {
    const int c = wu_id * 6 + c2;
    if (c < 8) {
      int s = c * 64 + lane, m = s >> 2, ko = (s & 3) ^ (m & 3);
      sp[c2] = (const char*)xb + (size_t)(prowbase + m) * (DM * 2) + ko * 16;
      stp[c2] = 64;
    } else if (c < 16) {
      int u = (c - 8) * 64 + lane, n = u >> 2, ko = (u & 3) ^ (n & 3);
      sp[c2] = BuBase + (size_t)(ko * 128 + n) * 16;
      stp[c2] = 8192;
    } else {
      int u = (c - 16) * 64 + lane, n = u >> 2, ko = (u & 3) ^ (n & 3);
      sp[c2] = BvBase + (size_t)(ko * 128 + n) * 16;
      stp[c2] = 8192;
    }
  }
  const int lc = lane & 15, q = lane >> 4;

  for (int kt = 0; kt < 24; ++kt) {
#pragma unroll
    for (int c2 = 0; c2 < 6; ++c2) {
      ASYNC16(sp[c2], (char*)Sh + (unsigned)((wu_id * 6 + c2) * 1024));
      sp[c2] += stp[c2];
    }
    __syncthreads();
    bf16x8 a[4], bu[4], bv[4];
#pragma unroll
    for (int i = 0; i < 4; ++i) {
      int m = wm * 64 + i * 16 + lc;
      a[i] = *(const bf16x8*)&Sh[(m * 4 + (q ^ (m & 3))) * 8];
    }
#pragma unroll
    for (int j = 0; j < 4; ++j) {
      int n = wn * 64 + j * 16 + lc;
      int slb = (n * 4 + (q ^ (n & 3))) * 8;
      bu[j] = *(const bf16x8*)&Sh[4096 + slb];
      bv[j] = *(const bf16x8*)&Sh[8192 + slb];
    }
#pragma unroll
    for (int i = 0; i < 4; ++i)
#pragma unroll
      for (int j = 0; j < 4; ++j) {
        accU[i][j] = __builtin_amdgcn_mfma_f32_16x16x32_bf16(a[i], bu[j], accU[i][j], 0, 0, 0);
        accV[i][j] = __builtin_amdgcn_mfma_f32_16x16x32_bf16(a[i], bv[j], accV[i][j], 0, 0, 0);
      }
    __syncthreads();
  }
  const int colbase = tn * 128 + wn * 64;
  const int rlane = (lane >> 4) * 4;
  const int clane = lane & 15;
#pragma unroll
  for (int i = 0; i < 4; ++i) {
#pragma unroll
    for (int r = 0; r < 4; ++r) {
      int rowIn = wm * 64 + i * 16 + rlane + r;
      if (tm * 128 + rowIn < Me) {
        int prow = prowbase + rowIn;
        float g = gate_b[prow];
        unsigned short* hp = h + (size_t)prow * HID + colbase + clane;
#pragma unroll
        for (int j = 0; j < 4; ++j) {
          float u_ = accU[i][j][r];
          float v_ = accV[i][j][r];
          float sv = u_ / (1.f + expf(-u_));
          hp[j * 16] = f2bf(sv * v_ * g);
        }
      }
    }
  }
}

// ---------------- FFN2: y += h @ Wd (split-K=4, atomic f32) ----------------
__global__ __launch_bounds__(256, 2)
void k_ffn2(const unsigned short* __restrict__ wdb, const unsigned short* __restrict__ h,
            const int* __restrict__ counts, const int* __restrict__ tlist,
            float* __restrict__ y)
{
  const int z = blockIdx.z;
  const int e = z >> 2, split = z & 3;
  const int Me = counts[e];
  const int tm = blockIdx.y;
  if (tm * 128 >= Me) return;
  const int tn = blockIdx.x;
  const int prowbase = padded_off(counts, e) + tm * 128;

  __shared__ __align__(16) unsigned short Sh[8192];  // [A 8KB][B 8KB]

  const int tid = threadIdx.x;
  const int lane = tid & 63;
  const int wv_ = tid >> 6;
  const int wm = wv_ >> 1, wn = wv_ & 1;
  const int wu_id = __builtin_amdgcn_readfirstlane(wv_);

  f32x4 acc[4][4];
#pragma unroll
  for (int i = 0; i < 4; ++i)
#pragma unroll
    for (int j = 0; j < 4; ++j)
#pragma unroll
      for (int k = 0; k < 4; ++k) acc[i][j][k] = 0.f;

  const char* BdBase = (const char*)wdb + ((size_t)((e * 6 + tn) * 64) << 13);

  const char* sp[4]; size_t stp[4];
#pragma unroll
  for (int c2 = 0; c2 < 4; ++c2) {
    const int c = wu_id * 4 + c2;
    if (c < 8) {
      int s = c * 64 + lane, m = s >> 2, ko = (s & 3) ^ (m & 3);
      sp[c2] = (const char*)h + (size_t)(prowbase + m) * (HID * 2) + split * 1024 + ko * 16;
      stp[c2] = 64;
    } else {
      int u = (c - 8) * 64 + lane, n = u >> 2, ko = (u & 3) ^ (n & 3);
      sp[c2] = BdBase + (size_t)split * 131072 + (size_t)(ko * 128 + n) * 16;
      stp[c2] = 8192;
    }
  }
  const int lc = lane & 15, q = lane >> 4;

  for (int kti = 0; kti < 16; ++kti) {
#pragma unroll
    for (int c2 = 0; c2 < 4; ++c2) {
      ASYNC16(sp[c2], (char*)Sh + (unsigned)((wu_id * 4 + c2) * 1024));
      sp[c2] += stp[c2];
    }
    __syncthreads();
    bf16x8 a[4], bfr[4];
#pragma unroll
    for (int i = 0; i < 4; ++i) {
      int m = wm * 64 + i * 16 + lc;
      a[i] = *(const bf16x8*)&Sh[(m * 4 + (q ^ (m & 3))) * 8];
    }
#pragma unroll
    for (int j = 0; j < 4; ++j) {
      int n = wn * 64 + j * 16 + lc;
      bfr[j] = *(const bf16x8*)&Sh[4096 + (n * 4 + (q ^ (n & 3))) * 8];
    }
#pragma unroll
    for (int i = 0; i < 4; ++i)
#pragma unroll
      for (int j = 0; j < 4; ++j)
        acc[i][j] = __builtin_amdgcn_mfma_f32_16x16x32_bf16(a[i], bfr[j], acc[i][j], 0, 0, 0);
    __syncthreads();
  }
  const int colbase = tn * 128 + wn * 64;
  const int rlane = (lane >> 4) * 4;
  const int clane = lane & 15;
#pragma unroll
  for (int i = 0; i < 4; ++i) {
#pragma unroll
    for (int r = 0; r < 4; ++r) {
      int rowIn = wm * 64 + i * 16 + rlane + r;
      if (tm * 128 + rowIn < Me) {
        int tok = tlist[prowbase + rowIn];
        float* yp = y + (size_t)tok * DM + colbase + clane;
#pragma unroll
        for (int j = 0; j < 4; ++j) atomicAdd(&yp[j * 16], acc[i][j][r]);
      }
    }
  }
}

extern "C" void kernel_launch(void* const* d_in, const int* in_sizes, int n_in,
                              void* d_out, int out_size, void* d_ws, size_t ws_size,
                              hipStream_t stream)
{
  const float* x   = (const float*)d_in[0];
  const float* wgw = (const float*)d_in[1];
  const float* wgb = (const float*)d_in[2];
  const float* Wu  = (const float*)d_in[3];
  const float* Wv  = (const float*)d_in[4];
  const float* Wd  = (const float*)d_in[5];
  float* out = (float*)d_out;

  // ws layout (~104.5 MB total)
  char* ws = (char*)d_ws;
  int*   counts = (int*)(ws + 0);                         // 8 ints
  int*   eidx   = (int*)(ws + 256);                       // 4096
  float* gatep  = (float*)(ws + 16640);                   // 4096
  int*   pos    = (int*)(ws + 33024);                     // 4096
  float* cepart = (float*)(ws + 49408);                   // 1024*8
  int*   tlist  = (int*)(ws + 82176);                     // 5120 (padded rows)
  float* gate_b = (float*)(ws + 102656);                  // 5120
  unsigned short* xb  = (unsigned short*)(ws + 123136);   // 5120*768 bf16 = 7.86 MB
  unsigned short* h   = (unsigned short*)(ws + 7987456);  // 5120*2048 bf16 = 21 MB
  unsigned short* wub = (unsigned short*)(ws + 28958976); // 25.2 MB
  unsigned short* wvb = (unsigned short*)(ws + 54124800); // 25.2 MB
  unsigned short* wdb = (unsigned short*)(ws + 79290624); // 25.2 MB

  hipMemsetAsync(counts, 0, 32, stream);
  k1_gate_convert<<<1024 + 4608, 256, 0, stream>>>(x, wgw, wgb, Wu, Wv, Wd,
                                                   eidx, gatep, pos, counts, cepart,
                                                   wub, wvb, wdb);
  k2_scatter_zero_aux<<<1537, 256, 0, stream>>>(x, eidx, gatep, pos, counts, cepart,
                                                tlist, gate_b, xb,
                                                out, out + (size_t)TOK * DM);
  k_ffn1<<<dim3(16, 32, 8), 256, 0, stream>>>(wub, wvb, xb, gate_b, counts, h);
  k_ffn2<<<dim3(6, 32, 32), 256, 0, stream>>>(wdb, h, counts, tlist, out);
}

// Round 7
// 343.235 us; speedup vs baseline: 1.2112x; 1.0953x over previous
//
#include <hip/hip_runtime.h>
#include <cstdint>
#include <cstddef>

#define TOK 4096
#define DM 768
#define HID 2048
#define NE 8

typedef __attribute__((ext_vector_type(8))) short bf16x8;
typedef __attribute__((ext_vector_type(4))) float f32x4;

// async global->LDS: dest = wave-uniform base + lane*16; SOURCE is per-lane.
#define ASYNC16(GP, LP) \
  __builtin_amdgcn_global_load_lds((__attribute__((address_space(1))) void*)(GP), \
                                   (__attribute__((address_space(3))) void*)(LP), 16, 0, 0)

__device__ __forceinline__ unsigned short f2bf(float f) {
  unsigned int u = __float_as_uint(f);
  u += 0x7FFF + ((u >> 16) & 1);   // RNE
  return (unsigned short)(u >> 16);
}
__device__ __forceinline__ unsigned int pack2(float a, float b) {
  return (unsigned)f2bf(a) | ((unsigned)f2bf(b) << 16);
}
__device__ __forceinline__ int padded_off(const int* counts, int e) {
  int o = 0;
  for (int i = 0; i < e; ++i) o += (counts[i] + 127) & ~127;
  return o;
}

// ---------------- K_gate: gating only (NO atomics) ----------------
__global__ __launch_bounds__(256)
void k_gate(const float* __restrict__ x, const float* __restrict__ wgw,
            const float* __restrict__ wgb,
            int* __restrict__ eidx, float* __restrict__ gatep,
            float* __restrict__ cepart)
{
  __shared__ float ce_loc[4][NE];
  const int lane = threadIdx.x & 63;
  const int w = threadIdx.x >> 6;
  const int t = blockIdx.x * 4 + w;
  float acc[NE];
#pragma unroll
  for (int e = 0; e < NE; ++e) acc[e] = 0.f;
  const float* xr = x + (size_t)t * DM;
#pragma unroll
  for (int j = 0; j < DM / 64; ++j) {
    float xv = xr[j * 64 + lane];
#pragma unroll
    for (int e = 0; e < NE; ++e) acc[e] += xv * wgw[e * DM + j * 64 + lane];
  }
#pragma unroll
  for (int e = 0; e < NE; ++e) {
    float v = acc[e];
#pragma unroll
    for (int off = 32; off >= 1; off >>= 1) v += __shfl_xor(v, off);
    acc[e] = v + wgb[e];
  }
  float mx = acc[0]; int ai = 0;
#pragma unroll
  for (int e = 1; e < NE; ++e) if (acc[e] > mx) { mx = acc[e]; ai = e; }
  float p[NE]; float se = 0.f;
#pragma unroll
  for (int e = 0; e < NE; ++e) { p[e] = expf(acc[e] - mx); se += p[e]; }
  float inv = 1.f / se;
  if (lane == 0) {
#pragma unroll
    for (int e = 0; e < NE; ++e) ce_loc[w][e] = p[e] * inv;
    eidx[t] = ai;
    gatep[t] = p[ai] * inv;
  }
  __syncthreads();
  if (threadIdx.x < NE) {
    float s = ce_loc[0][threadIdx.x] + ce_loc[1][threadIdx.x]
            + ce_loc[2][threadIdx.x] + ce_loc[3][threadIdx.x];
    cepart[blockIdx.x * NE + threadIdx.x] = s;
  }
}

// ---------------- K_convert: fp32 weights -> bf16 blobs ----------------
// Blob: per (expert, 128-col tile): K/32 slabs of 8192 B; slab unit = ko*128+n.
__global__ __launch_bounds__(256)
void k_convert(const float* __restrict__ Wu, const float* __restrict__ Wv,
               const float* __restrict__ Wd,
               unsigned short* __restrict__ wub, unsigned short* __restrict__ wvb,
               unsigned short* __restrict__ wdb)
{
  const int cb = blockIdx.x;               // 0..4607
  const int seg = cb / 1536;               // 0=Wu 1=Wv 2=Wd
  const int r = cb % 1536;
  const int e = r / 192;
  const int rem = r % 192;
  const float* W;
  unsigned short* blobbase;
  int N, nt, kt2;
  if (seg < 2) {
    N = HID; nt = rem / 12; kt2 = rem % 12;            // K=768: 12 x 64k
    W = ((seg == 0) ? Wu : Wv) + (size_t)e * DM * HID;
    blobbase = ((seg == 0) ? wub : wvb) + ((size_t)((e * 16 + nt) * 24) << 12);
  } else {
    N = DM; nt = rem / 32; kt2 = rem % 32;             // K=2048: 32 x 64k
    W = Wd + (size_t)e * HID * DM;
    blobbase = wdb + ((size_t)((e * 6 + nt) * 64) << 12);
  }
  const int t = threadIdx.x;
  const int n4 = t & 31, ko8 = t >> 5;                 // 32 n-quads x 8 k-octets
  const float* src = W + (size_t)(kt2 * 64 + ko8 * 8) * N + nt * 128 + n4 * 4;
  float4 f[8];
#pragma unroll
  for (int j = 0; j < 8; ++j) f[j] = *(const float4*)(src + (size_t)j * N);
  const int kt = kt2 * 2 + (ko8 >> 2), ko = ko8 & 3;
  unsigned short* dst = blobbase + ((size_t)kt << 12) + (size_t)(ko * 128 + n4 * 4) * 8;
#pragma unroll
  for (int i = 0; i < 4; ++i) {
    uint4 u;
    u.x = pack2(((const float*)&f[0])[i], ((const float*)&f[1])[i]);
    u.y = pack2(((const float*)&f[2])[i], ((const float*)&f[3])[i]);
    u.z = pack2(((const float*)&f[4])[i], ((const float*)&f[5])[i]);
    u.w = pack2(((const float*)&f[6])[i], ((const float*)&f[7])[i]);
    *(uint4*)(dst + i * 8) = u;
  }
}

// ---------------- K_count: single-block counting sort + aux ----------------
__global__ __launch_bounds__(256)
void k_count(const int* __restrict__ eidx, const float* __restrict__ gatep,
             const float* __restrict__ cepart,
             int* __restrict__ prow_arr, int* __restrict__ tlist,
             float* __restrict__ gate_b, int* __restrict__ counts_g,
             float* __restrict__ aux_out)
{
  __shared__ int hist[256][NE];
  __shared__ float fs[256][NE];
  __shared__ int po_s[NE], cnt_s[NE];
  const int tid = threadIdx.x;
  int own[NE], v[NE], el[16];
#pragma unroll
  for (int e = 0; e < NE; ++e) own[e] = 0;
#pragma unroll
  for (int j = 0; j < 16; ++j) {
    el[j] = eidx[tid * 16 + j];
#pragma unroll
    for (int e = 0; e < NE; ++e) own[e] += (el[j] == e) ? 1 : 0;
  }
#pragma unroll
  for (int e = 0; e < NE; ++e) { v[e] = own[e]; hist[tid][e] = v[e]; }
  __syncthreads();
  for (int st = 1; st < 256; st <<= 1) {
    int add[NE];
#pragma unroll
    for (int e = 0; e < NE; ++e) add[e] = (tid >= st) ? hist[tid - st][e] : 0;
    __syncthreads();
#pragma unroll
    for (int e = 0; e < NE; ++e) { v[e] += add[e]; hist[tid][e] = v[e]; }
    __syncthreads();
  }
  if (tid == 0) {
    int o = 0;
#pragma unroll
    for (int e = 0; e < NE; ++e) {
      int c = hist[255][e];
      cnt_s[e] = c; counts_g[e] = c; po_s[e] = o;
      o += (c + 127) & ~127;
    }
  }
  __syncthreads();
  int run[NE];
#pragma unroll
  for (int e = 0; e < NE; ++e) run[e] = po_s[e] + v[e] - own[e];
#pragma unroll
  for (int j = 0; j < 16; ++j) {
    const int t = tid * 16 + j;
    const int e = el[j];
    int p = 0;
#pragma unroll
    for (int k = 0; k < NE; ++k) if (e == k) p = run[k]++;
    prow_arr[t] = p;
    tlist[p] = t;
    gate_b[p] = gatep[t];
  }
  // aux reduce
  float s[NE];
#pragma unroll
  for (int e = 0; e < NE; ++e) s[e] = 0.f;
  for (int bb = tid; bb < 1024; bb += 256)
#pragma unroll
    for (int e = 0; e < NE; ++e) s[e] += cepart[bb * NE + e];
#pragma unroll
  for (int e = 0; e < NE; ++e) fs[tid][e] = s[e];
  __syncthreads();
  for (int st = 128; st > 0; st >>= 1) {
    if (tid < st)
#pragma unroll
      for (int e = 0; e < NE; ++e) fs[tid][e] += fs[tid + st][e];
    __syncthreads();
  }
  if (tid == 0) {
    float aux = 0.f;
    for (int e = 0; e < NE; ++e)
      aux += ((float)cnt_s[e] / 4096.f) * (fs[0][e] / 4096.f);
    aux_out[0] = 0.05f * 8.f * aux;
  }
}

// ---------------- K2: scatter x rows (row-major bf16) + zero y ----------------
__global__ __launch_bounds__(256)
void k2_scatter_zero(const float* __restrict__ x, const int* __restrict__ prow_arr,
                     unsigned short* __restrict__ xb, float* __restrict__ y)
{
  const int b = blockIdx.x;
  if (b < 1024) {
    const int lane = threadIdx.x & 63;
    const int w = threadIdx.x >> 6;
    const int t = b * 4 + w;
    const int prow = prow_arr[t];
    const float4* src4 = (const float4*)(x + (size_t)t * DM);
    uint2* dst = (uint2*)(xb + (size_t)prow * DM);
#pragma unroll
    for (int c = 0; c < 3; ++c) {
      float4 v = src4[lane + c * 64];
      uint2 d; d.x = pack2(v.x, v.y); d.y = pack2(v.z, v.w);
      dst[lane + c * 64] = d;
    }
  } else {
    float4* y4 = (float4*)y;
    const int base = (b - 1024) * 1536 + threadIdx.x;
#pragma unroll
    for (int c = 0; c < 6; ++c) {
      float4 z; z.x = 0.f; z.y = 0.f; z.z = 0.f; z.w = 0.f;
      y4[base + c * 256] = z;
    }
  }
}

// ---------------- FFN1: h = silu(x@Wu)*(x@Wv)*gate ----------------
// 128M x 128N, BK=64 (2 sub-iters of 32), waves 2x2. LDS 48 KB dbl-region.
__global__ __launch_bounds__(256, 2)
void k_ffn1(const unsigned short* __restrict__ wub, const unsigned short* __restrict__ wvb,
            const unsigned short* __restrict__ xb, const float* __restrict__ gate_b,
            const int* __restrict__ counts, unsigned short* __restrict__ h)
{
  const int e = blockIdx.z;
  const int Me = counts[e];
  const int tm = blockIdx.y;
  if (tm * 128 >= Me) return;
  const int tn = blockIdx.x;
  const int prowbase = padded_off(counts, e) + tm * 128;

  // regions (8 KB each): [A0][Bu0][Bv0][A1][Bu1][Bv1]
  __shared__ __align__(16) unsigned short Sh[24576];

  const int tid = threadIdx.x;
  const int lane = tid & 63;
  const int wv_ = tid >> 6;
  const int wm = wv_ >> 1, wn = wv_ & 1;
  const int wu_id = __builtin_amdgcn_readfirstlane(wv_);

  f32x4 accU[4][4], accV[4][4];
#pragma unroll
  for (int i = 0; i < 4; ++i)
#pragma unroll
    for (int j = 0; j < 4; ++j)
#pragma unroll
      for (int k = 0; k < 4; ++k) { accU[i][j][k] = 0.f; accV[i][j][k] = 0.f; }

  const char* BuBase = (const char*)wub + ((size_t)((e * 16 + tn) * 24) << 13);
  const char* BvBase = (const char*)wvb + ((size_t)((e * 16 + tn) * 24) << 13);

  const char* sp[12]; size_t stp[12];
#pragma unroll
  for (int c2 = 0; c2 < 12; ++c2) {
    const int c = wu_id * 12 + c2;
    const int reg = c >> 3, i8 = c & 7;
    const int sub = (reg >= 3);
    const int rr = (reg >= 3) ? reg - 3 : reg;
    const int s = i8 * 64 + lane;
    if (rr == 0) {
      int m = s >> 2, ko = (s & 3) ^ (m & 3);
      sp[c2] = (const char*)xb + (size_t)(prowbase + m) * (DM * 2) + sub * 64 + ko * 16;
      stp[c2] = 128;
    } else {
      int n = s >> 2, ko = (s & 3) ^ (n & 3);
      const char* base = (rr == 1) ? BuBase : BvBase;
      sp[c2] = base + (size_t)sub * 8192 + (size_t)(ko * 128 + n) * 16;
      stp[c2] = 16384;
    }
  }
  const int lc = lane & 15, q = lane >> 4;

  for (int kt2 = 0; kt2 < 12; ++kt2) {
#pragma unroll
    for (int c2 = 0; c2 < 12; ++c2) {
      ASYNC16(sp[c2], (char*)Sh + (unsigned)((wu_id * 12 + c2) * 1024));
      sp[c2] += stp[c2];
    }
    __syncthreads();
#pragma unroll
    for (int sub = 0; sub < 2; ++sub) {
      const int sb = sub * 12288;
      bf16x8 a[4], bu[4], bv[4];
#pragma unroll
      for (int i = 0; i < 4; ++i) {
        int m = wm * 64 + i * 16 + lc;
        a[i] = *(const bf16x8*)&Sh[sb + (m * 4 + (q ^ (m & 3))) * 8];
      }
#pragma unroll
      for (int j = 0; j < 4; ++j) {
        int n = wn * 64 + j * 16 + lc;
        int slb = (n * 4 + (q ^ (n & 3))) * 8;
        bu[j] = *(const bf16x8*)&Sh[sb + 4096 + slb];
        bv[j] = *(const bf16x8*)&Sh[sb + 8192 + slb];
      }
#pragma unroll
      for (int i = 0; i < 4; ++i)
#pragma unroll
        for (int j = 0; j < 4; ++j) {
          accU[i][j] = __builtin_amdgcn_mfma_f32_16x16x32_bf16(a[i], bu[j], accU[i][j], 0, 0, 0);
          accV[i][j] = __builtin_amdgcn_mfma_f32_16x16x32_bf16(a[i], bv[j], accV[i][j], 0, 0, 0);
        }
    }
    __syncthreads();
  }
  const int colbase = tn * 128 + wn * 64;
  const int rlane = (lane >> 4) * 4;
  const int clane = lane & 15;
#pragma unroll
  for (int i = 0; i < 4; ++i) {
#pragma unroll
    for (int r = 0; r < 4; ++r) {
      int rowIn = wm * 64 + i * 16 + rlane + r;
      if (tm * 128 + rowIn < Me) {
        int prow = prowbase + rowIn;
        float g = gate_b[prow];
        unsigned short* hp = h + (size_t)prow * HID + colbase + clane;
#pragma unroll
        for (int j = 0; j < 4; ++j) {
          float u_ = accU[i][j][r];
          float v_ = accV[i][j][r];
          float sv = u_ / (1.f + expf(-u_));
          hp[j * 16] = f2bf(sv * v_ * g);
        }
      }
    }
  }
}

// ---------------- FFN2: y += h @ Wd (split-K=4, atomic f32), BK=64 ----------------
__global__ __launch_bounds__(256, 2)
void k_ffn2(const unsigned short* __restrict__ wdb, const unsigned short* __restrict__ h,
            const int* __restrict__ counts, const int* __restrict__ tlist,
            float* __restrict__ y)
{
  const int z = blockIdx.z;
  const int e = z >> 2, split = z & 3;
  const int Me = counts[e];
  const int tm = blockIdx.y;
  if (tm * 128 >= Me) return;
  const int tn = blockIdx.x;
  const int prowbase = padded_off(counts, e) + tm * 128;

  // regions (8 KB each): [A0][B0][A1][B1]
  __shared__ __align__(16) unsigned short Sh[16384];

  const int tid = threadIdx.x;
  const int lane = tid & 63;
  const int wv_ = tid >> 6;
  const int wm = wv_ >> 1, wn = wv_ & 1;
  const int wu_id = __builtin_amdgcn_readfirstlane(wv_);

  f32x4 acc[4][4];
#pragma unroll
  for (int i = 0; i < 4; ++i)
#pragma unroll
    for (int j = 0; j < 4; ++j)
#pragma unroll
      for (int k = 0; k < 4; ++k) acc[i][j][k] = 0.f;

  const char* BdBase = (const char*)wdb + ((size_t)((e * 6 + tn) * 64) << 13);

  const char* sp[8]; size_t stp[8];
#pragma unroll
  for (int c2 = 0; c2 < 8; ++c2) {
    const int c = wu_id * 8 + c2;
    const int reg = c >> 3, i8 = c & 7;         // reg: 0=A0 1=B0 2=A1 3=B1
    const int sub = reg >> 1;
    const int s = i8 * 64 + lane;
    if ((reg & 1) == 0) {
      int m = s >> 2, ko = (s & 3) ^ (m & 3);
      sp[c2] = (const char*)h + (size_t)(prowbase + m) * (HID * 2)
             + split * 1024 + sub * 64 + ko * 16;
      stp[c2] = 128;
    } else {
      int n = s >> 2, ko = (s & 3) ^ (n & 3);
      sp[c2] = BdBase + (size_t)(split * 16 + sub) * 8192 + (size_t)(ko * 128 + n) * 16;
      stp[c2] = 16384;
    }
  }
  const int lc = lane & 15, q = lane >> 4;

  for (int kti = 0; kti < 8; ++kti) {
#pragma unroll
    for (int c2 = 0; c2 < 8; ++c2) {
      ASYNC16(sp[c2], (char*)Sh + (unsigned)((wu_id * 8 + c2) * 1024));
      sp[c2] += stp[c2];
    }
    __syncthreads();
#pragma unroll
    for (int sub = 0; sub < 2; ++sub) {
      const int sb = sub * 8192;
      bf16x8 a[4], bfr[4];
#pragma unroll
      for (int i = 0; i < 4; ++i) {
        int m = wm * 64 + i * 16 + lc;
        a[i] = *(const bf16x8*)&Sh[sb + (m * 4 + (q ^ (m & 3))) * 8];
      }
#pragma unroll
      for (int j = 0; j < 4; ++j) {
        int n = wn * 64 + j * 16 + lc;
        bfr[j] = *(const bf16x8*)&Sh[sb + 4096 + (n * 4 + (q ^ (n & 3))) * 8];
      }
#pragma unroll
      for (int i = 0; i < 4; ++i)
#pragma unroll
        for (int j = 0; j < 4; ++j)
          acc[i][j] = __builtin_amdgcn_mfma_f32_16x16x32_bf16(a[i], bfr[j], acc[i][j], 0, 0, 0);
    }
    __syncthreads();
  }
  const int colbase = tn * 128 + wn * 64;
  const int rlane = (lane >> 4) * 4;
  const int clane = lane & 15;
#pragma unroll
  for (int i = 0; i < 4; ++i) {
#pragma unroll
    for (int r = 0; r < 4; ++r) {
      int rowIn = wm * 64 + i * 16 + rlane + r;
      if (tm * 128 + rowIn < Me) {
        int tok = tlist[prowbase + rowIn];
        float* yp = y + (size_t)tok * DM + colbase + clane;
#pragma unroll
        for (int j = 0; j < 4; ++j) atomicAdd(&yp[j * 16], acc[i][j][r]);
      }
    }
  }
}

extern "C" void kernel_launch(void* const* d_in, const int* in_sizes, int n_in,
                              void* d_out, int out_size, void* d_ws, size_t ws_size,
                              hipStream_t stream)
{
  const float* x   = (const float*)d_in[0];
  const float* wgw = (const float*)d_in[1];
  const float* wgb = (const float*)d_in[2];
  const float* Wu  = (const float*)d_in[3];
  const float* Wv  = (const float*)d_in[4];
  const float* Wd  = (const float*)d_in[5];
  float* out = (float*)d_out;

  char* ws = (char*)d_ws;
  int*   counts = (int*)(ws + 0);                         // 8 ints
  int*   eidx   = (int*)(ws + 256);                       // 4096
  float* gatep  = (float*)(ws + 16640);                   // 4096
  int*   prow   = (int*)(ws + 33024);                     // 4096
  float* cepart = (float*)(ws + 49408);                   // 1024*8
  int*   tlist  = (int*)(ws + 82176);                     // 5120 (padded rows)
  float* gate_b = (float*)(ws + 102656);                  // 5120
  unsigned short* xb  = (unsigned short*)(ws + 123136);   // 5120*768 bf16
  unsigned short* h   = (unsigned short*)(ws + 7987456);  // 5120*2048 bf16
  unsigned short* wub = (unsigned short*)(ws + 28958976); // 25.2 MB
  unsigned short* wvb = (unsigned short*)(ws + 54124800); // 25.2 MB
  unsigned short* wdb = (unsigned short*)(ws + 79290624); // 25.2 MB

  k_gate<<<1024, 256, 0, stream>>>(x, wgw, wgb, eidx, gatep, cepart);
  k_convert<<<4608, 256, 0, stream>>>(Wu, Wv, Wd, wub, wvb, wdb);
  k_count<<<1, 256, 0, stream>>>(eidx, gatep, cepart, prow, tlist, gate_b,
                                 counts, out + (size_t)TOK * DM);
  k2_scatter_zero<<<1536, 256, 0, stream>>>(x, prow, xb, out);
  k_ffn1<<<dim3(16, 32, 8), 256, 0, stream>>>(wub, wvb, xb, gate_b, counts, h);
  k_ffn2<<<dim3(6, 32, 32), 256, 0, stream>>>(wdb, h, counts, tlist, out);
}